// Round 11
// baseline (253.323 us; speedup 1.0000x reference)
//
#include <hip/hip_runtime.h>

typedef __attribute__((ext_vector_type(8))) short bf16x8;
typedef __attribute__((ext_vector_type(4))) float f32x4;

#define DEVICE __device__ __forceinline__

static constexpr int Tc = 2048;     // seq len
static constexpr int Dc = 2048;     // model dim
static constexpr int Hc = 16;       // heads
static constexpr int HD = 128;      // head dim
static constexpr int MR = 4096;     // B*T rows
static constexpr int NQKV = 6144;   // 3*D

DEVICE float bf2f(unsigned short u) {
  unsigned int t = ((unsigned int)u) << 16;
  float f; __builtin_memcpy(&f, &t, 4); return f;
}
DEVICE unsigned short f2bf(float f) {
  unsigned int t; __builtin_memcpy(&t, &f, 4);
  unsigned int r = (t + 0x7fffu + ((t >> 16) & 1u)) >> 16;
  return (unsigned short)r;
}

DEVICE void async_cp16(const void* g, void* lds) {
  __builtin_amdgcn_global_load_lds((const __attribute__((address_space(1))) void*)g,
                                   (__attribute__((address_space(3))) void*)lds, 16, 0, 0);
}

// epilogue LDS tile swizzle: row t (256B rows), byte col d2; bijective per row,
// spreads both row-major 16B reads and col-major scalar reads across banks.
DEVICE int lsw(int t, int d2) {
  return t * 256 + (d2 ^ ((((t & 7) ^ ((t >> 3) & 7)) << 4)));
}

// ---------------- RoPE cos/sin table: cs[t][j] = (cos, sin), j in [0,64) ----
__global__ void rope_table_kernel(float2* cs) {
  int t = blockIdx.x;
  int j = threadIdx.x;                   // 0..63
  float inv = powf(10000.0f, -(float)(2 * j) / 128.0f);
  float ang = (float)t * inv;
  cs[t * 64 + j] = make_float2(cosf(ang), sinf(ang));
}

// ---------------- fp32 -> bf16 elementwise (vectorized) ---------------------
__global__ void f32_to_bf16_kernel(const float* __restrict__ in,
                                   unsigned short* __restrict__ out, int n) {
  int i = (blockIdx.x * blockDim.x + threadIdx.x) * 4;
  if (i >= n) return;
  float4 v = *(const float4*)(in + i);
  ushort4 o;
  o.x = f2bf(v.x); o.y = f2bf(v.y); o.z = f2bf(v.z); o.w = f2bf(v.w);
  *(ushort4*)(out + i) = o;
}

// ------------- transpose fp32 (R x C) -> bf16 (C x R), 64x64 tiles ---------
__global__ __launch_bounds__(256)
void transpose_f32_bf16_kernel(const float* __restrict__ in,
                               unsigned short* __restrict__ out,
                               int R, int C) {
  __shared__ float tile[64][68];
  int c0 = blockIdx.x * 64, r0 = blockIdx.y * 64;
  int tid = threadIdx.x;
#pragma unroll
  for (int it = 0; it < 4; ++it) {
    int idx = it * 256 + tid;        // 0..1023
    int r = idx >> 4;                // 0..63
    int c = (idx & 15) * 4;          // 0..60
    float4 v = *(const float4*)&in[(size_t)(r0 + r) * C + c0 + c];
    tile[r][c] = v.x; tile[r][c + 1] = v.y;
    tile[r][c + 2] = v.z; tile[r][c + 3] = v.w;
  }
  __syncthreads();
#pragma unroll
  for (int it = 0; it < 2; ++it) {
    int idx = it * 256 + tid;        // 0..511
    int r = idx >> 3;                // out row (c-dim) 0..63
    int c = (idx & 7) * 8;           // out col base (r-dim)
    bf16x8 ov;
#pragma unroll
    for (int i = 0; i < 8; ++i) ov[i] = (short)f2bf(tile[c + i][r]);
    *(bf16x8*)&out[(size_t)(c0 + r) * R + r0 + c] = ov;
  }
}

// ========== QKV GEMM (double-buffered, counted vmcnt) + fused epilogue ======
// Per K-tile: s_barrier (compute(t-1) reads done) -> stage(t+1, buf^1) ->
// vmcnt(8) (tile t landed; next tile's 8 stay in flight) -> s_barrier ->
// compute(t). Staging latency hides under previous tile's compute.
__global__ __launch_bounds__(256, 2)
void gemm_qkv_kernel(const unsigned short* __restrict__ A,
                     const unsigned short* __restrict__ Bt,
                     const float2* __restrict__ cs,
                     unsigned short* __restrict__ qh,
                     unsigned short* __restrict__ kh,
                     unsigned short* __restrict__ vt) {
  const int N = NQKV, K = Dc;
  __shared__ __align__(16) unsigned short sh[4 * 128 * 64];   // 64KB
  // A bufs: sh+0, sh+8192 ; B bufs: sh+16384, sh+24576 (elements)

  int nbx = N >> 7;                      // 48
  int nwg = gridDim.x;                   // 1536
  int wg = blockIdx.x;
  int cpx = nwg >> 3;
  wg = (wg & 7) * cpx + (wg >> 3);       // XCD-contiguous (bijective: nwg%8==0)
  int gsize = nbx * 8;                   // GROUP_M=8 supertiles for L2 reuse
  int g = wg / gsize, rem = wg - g * gsize;
  int by = g * 8 + (rem & 7), bx = rem >> 3;
  int m0 = by << 7, n0 = bx << 7;

  int tid = threadIdx.x, lane = tid & 63, wid = tid >> 6;
  int wm = (wid >> 1) << 6, wn = (wid & 1) << 6;

  f32x4 acc[4][4] = {};

  auto stage = [&](int kt, int buf) {    // 8 vmem loads per thread
    int k0 = kt << 6;
#pragma unroll
    for (int r = 0; r < 4; ++r) {
      int p = r * 4096 + wid * 1024 + lane * 16;   // byte offset in tile
      int row = p >> 7;
      int cb = (p & 127) ^ ((row & 7) << 4);       // pre-swizzled source col
      const char* ga = (const char*)A + ((size_t)(m0 + row) * K + k0) * 2 + cb;
      async_cp16(ga, (char*)(sh + buf * 8192) + r * 4096 + wid * 1024);
      const char* gb = (const char*)Bt + ((size_t)(n0 + row) * K + k0) * 2 + cb;
      async_cp16(gb, (char*)(sh + 16384 + buf * 8192) + r * 4096 + wid * 1024);
    }
  };

  int nkt = K >> 6;                      // 32
  stage(0, 0);
#pragma unroll 1
  for (int t = 0; t < nkt; ++t) {
    asm volatile("s_barrier" ::: "memory");        // compute(t-1) reads done
    if (t + 1 < nkt) {
      stage(t + 1, (t + 1) & 1);
      asm volatile("s_waitcnt vmcnt(8)" ::: "memory");  // tile t landed
    } else {
      asm volatile("s_waitcnt vmcnt(0)" ::: "memory");
    }
    asm volatile("s_barrier" ::: "memory");        // all waves' tile t ready
    const char* Ab = (const char*)(sh + (t & 1) * 8192);
    const char* Bb = (const char*)(sh + 16384 + (t & 1) * 8192);

#pragma unroll
    for (int ks = 0; ks < 2; ++ks) {
      bf16x8 af[4], bfr[4];
#pragma unroll
      for (int mi = 0; mi < 4; ++mi) {
        int row = wm + mi * 16 + (lane & 15);
        int cb = (ks * 64 + ((lane >> 4) << 4)) ^ ((row & 7) << 4);
        af[mi] = *(const bf16x8*)(Ab + row * 128 + cb);
      }
#pragma unroll
      for (int ni = 0; ni < 4; ++ni) {
        int row = wn + ni * 16 + (lane & 15);
        int cb = (ks * 64 + ((lane >> 4) << 4)) ^ ((row & 7) << 4);
        bfr[ni] = *(const bf16x8*)(Bb + row * 128 + cb);
      }
#pragma unroll
      for (int mi = 0; mi < 4; ++mi)
#pragma unroll
        for (int ni = 0; ni < 4; ++ni)
          acc[mi][ni] = __builtin_amdgcn_mfma_f32_16x16x32_bf16(
              af[mi], bfr[ni], acc[mi][ni], 0, 0, 0);
    }
  }

  // ---- epilogue: acc -> LDS (bf16, swizzled; reuses first 32KB) ----
  __syncthreads();   // all waves done with main loop LDS
#pragma unroll
  for (int mi = 0; mi < 4; ++mi)
#pragma unroll
    for (int ni = 0; ni < 4; ++ni)
#pragma unroll
      for (int r = 0; r < 4; ++r) {
        int t_ = wm + mi * 16 + ((lane >> 4) << 2) + r;
        int d_ = wn + ni * 16 + (lane & 15);
        *(unsigned short*)((char*)sh + lsw(t_, d_ * 2)) = f2bf(acc[mi][ni][r]);
      }
  __syncthreads();

  int sector = n0 >> 11;                 // 0=Q, 1=K, 2=V
  int h = (n0 & 2047) >> 7;
  if (sector < 2) {
    unsigned short* dst = sector ? kh : qh;
#pragma unroll
    for (int it = 0; it < 4; ++it) {
      int idx = it * 256 + tid;
      int r = idx >> 3, j0 = (idx & 7) * 8;
      int m = m0 + r;
      int t = m & (Tc - 1), b = m >> 11;
      bf16x8 o1, o2;
#pragma unroll
      for (int i = 0; i < 8; ++i) {
        float q1 = bf2f(*(const unsigned short*)((const char*)sh + lsw(r, (j0 + i) * 2)));
        float q2 = bf2f(*(const unsigned short*)((const char*)sh + lsw(r, (j0 + i + 64) * 2)));
        float2 c = cs[t * 64 + j0 + i];
        o1[i] = (short)f2bf(q1 * c.x - q2 * c.y);
        o2[i] = (short)f2bf(q2 * c.x + q1 * c.y);
      }
      size_t ob = ((size_t)(b * Hc + h) * Tc + t) * HD;
      *(bf16x8*)(dst + ob + j0) = o1;
      *(bf16x8*)(dst + ob + 64 + j0) = o2;
    }
  } else {
    int bh = (m0 >> 11) * Hc + h;
    int tb = m0 & (Tc - 1);
#pragma unroll
    for (int it = 0; it < 8; ++it) {
      int idx = it * 256 + tid;
      int d = idx >> 4, tc = idx & 15;
      bf16x8 o;
#pragma unroll
      for (int i = 0; i < 8; ++i)
        o[i] = (short)*(const unsigned short*)((const char*)sh + lsw(tc * 8 + i, d * 2));
      *(bf16x8*)(vt + (size_t)(bh * HD + d) * Tc + tb + tc * 8) = o;
    }
  }
}

// ------- 128x128 bf16 GEMM (double-buffered, counted vmcnt), out-proj -------
__global__ __launch_bounds__(256, 2)
void gemm_bt_kernel(const unsigned short* __restrict__ A,
                    const unsigned short* __restrict__ Bt,
                    float* __restrict__ C, int M, int N, int K) {
  __shared__ __align__(16) unsigned short As[2][128 * 64];
  __shared__ __align__(16) unsigned short Bs[2][128 * 64];

  int nbx = N >> 7;
  int nwg = gridDim.x;
  int wg = blockIdx.x;
  int cpx = nwg >> 3;
  wg = (wg & 7) * cpx + (wg >> 3);
  int gsize = nbx * 8;
  int g = wg / gsize, rem = wg - g * gsize;
  int by = g * 8 + (rem & 7), bx = rem >> 3;
  int m0 = by << 7, n0 = bx << 7;

  int tid = threadIdx.x, lane = tid & 63, wid = tid >> 6;
  int wm = (wid >> 1) << 6, wn = (wid & 1) << 6;

  f32x4 acc[4][4] = {};

  auto stage = [&](int kt, int buf) {
    int k0 = kt << 6;
#pragma unroll
    for (int r = 0; r < 4; ++r) {
      int p = r * 4096 + wid * 1024 + lane * 16;
      int row = p >> 7;
      int cb = (p & 127) ^ ((row & 7) << 4);
      const char* ga = (const char*)A + ((size_t)(m0 + row) * K + k0) * 2 + cb;
      async_cp16(ga, (char*)&As[buf][0] + r * 4096 + wid * 1024);
      const char* gb = (const char*)Bt + ((size_t)(n0 + row) * K + k0) * 2 + cb;
      async_cp16(gb, (char*)&Bs[buf][0] + r * 4096 + wid * 1024);
    }
  };

  int nkt = K >> 6;
  stage(0, 0);
#pragma unroll 1
  for (int t = 0; t < nkt; ++t) {
    asm volatile("s_barrier" ::: "memory");
    if (t + 1 < nkt) {
      stage(t + 1, (t + 1) & 1);
      asm volatile("s_waitcnt vmcnt(8)" ::: "memory");
    } else {
      asm volatile("s_waitcnt vmcnt(0)" ::: "memory");
    }
    asm volatile("s_barrier" ::: "memory");
    const char* Ab = (const char*)&As[t & 1][0];
    const char* Bb = (const char*)&Bs[t & 1][0];

#pragma unroll
    for (int ks = 0; ks < 2; ++ks) {
      bf16x8 af[4], bfr[4];
#pragma unroll
      for (int mi = 0; mi < 4; ++mi) {
        int row = wm + mi * 16 + (lane & 15);
        int cb = (ks * 64 + ((lane >> 4) << 4)) ^ ((row & 7) << 4);
        af[mi] = *(const bf16x8*)(Ab + row * 128 + cb);
      }
#pragma unroll
      for (int ni = 0; ni < 4; ++ni) {
        int row = wn + ni * 16 + (lane & 15);
        int cb = (ks * 64 + ((lane >> 4) << 4)) ^ ((row & 7) << 4);
        bfr[ni] = *(const bf16x8*)(Bb + row * 128 + cb);
      }
#pragma unroll
      for (int mi = 0; mi < 4; ++mi)
#pragma unroll
        for (int ni = 0; ni < 4; ++ni)
          acc[mi][ni] = __builtin_amdgcn_mfma_f32_16x16x32_bf16(
              af[mi], bfr[ni], acc[mi][ni], 0, 0, 0);
    }
  }

#pragma unroll
  for (int mi = 0; mi < 4; ++mi)
#pragma unroll
    for (int ni = 0; ni < 4; ++ni)
#pragma unroll
      for (int r = 0; r < 4; ++r) {
        int row = m0 + wm + mi * 16 + ((lane >> 4) << 2) + r;
        int col = n0 + wn + ni * 16 + (lane & 15);
        C[(size_t)row * N + col] = acc[mi][ni][r];
      }
}

// ---------------- causal flash attention (round-8 proven version) -----------
__global__ __launch_bounds__(512, 1)
void attn_kernel(const unsigned short* __restrict__ qh,
                 const unsigned short* __restrict__ kh,
                 const unsigned short* __restrict__ vt,
                 unsigned short* __restrict__ ao) {
  const float SCL2 = 0.08838834764831845f * 1.4426950408889634f;  // scale*log2e
  int bh = blockIdx.x;                       // 0..31
  int pairp = blockIdx.y;                    // 0..7
  int b = bh >> 4, h = bh & 15;

  __shared__ unsigned short Ks[3][64 * 128];   // 3 x 16KB, 256B rows, swizzled
  __shared__ unsigned short Vs[3][128 * 64];   // 3 x 16KB, V^T rows=d, 128B
  __shared__ unsigned short Ps[8][16 * 64];    // 16KB, per-wave P, 128B rows

  int tid = threadIdx.x, lane = tid & 63, wid = tid >> 6;

  const unsigned short* Kg = kh + (size_t)bh * Tc * HD;
  const unsigned short* Vg = vt + (size_t)bh * HD * Tc;

  auto stage = [&](int kt, int buf) {        // 4 vmem loads per thread
#pragma unroll
    for (int r = 0; r < 2; ++r) {
      int p = r * 8192 + wid * 1024 + lane * 16;
      {
        int row = p >> 8, cb = p & 255;
        const char* g = (const char*)Kg + ((size_t)(kt * 64 + row)) * 256 +
                        (cb ^ ((row & 7) << 4));
        async_cp16(g, (char*)&Ks[buf][0] + r * 8192 + wid * 1024);
      }
      {
        int d = p >> 7, cb = p & 127;
        const char* g = (const char*)Vg + (size_t)d * (Tc * 2) + kt * 128 +
                        (cb ^ ((d & 7) << 4));
        async_cp16(g, (char*)&Vs[buf][0] + r * 8192 + wid * 1024);
      }
    }
  };

#pragma unroll 1
  for (int pass = 0; pass < 2; ++pass) {
    int qt = pass ? (15 - pairp) : pairp;
    const unsigned short* Qg = qh + ((size_t)bh * Tc + qt * 128) * HD;

    // Q fragments direct from global; drain so loop vmcnt counts stay exact
    bf16x8 qf[4];
#pragma unroll
    for (int ks = 0; ks < 4; ++ks) {
      int row = wid * 16 + (lane & 15);
      qf[ks] = *(const bf16x8*)((const char*)Qg + row * 256 + ks * 64 +
                                ((lane >> 4) << 4));
    }
    asm volatile("s_waitcnt vmcnt(0)" ::: "memory");

    f32x4 oacc[8] = {};
    float mrow[4], lrow[4];
#pragma unroll
    for (int r = 0; r < 4; ++r) { mrow[r] = -1e30f; lrow[r] = 0.f; }

    int nkt = 2 * (qt + 1);
    __syncthreads();     // pass boundary: prior pass's LDS reads done
    stage(0, 0);
    stage(1, 1);         // nkt >= 2 always
#pragma unroll 1
    for (int kt = 0; kt < nkt; ++kt) {
      // wait for tile kt (own loads), then barrier -> all threads' loads done
      if (kt + 1 < nkt)
        asm volatile("s_waitcnt vmcnt(4)" ::: "memory");
      else
        asm volatile("s_waitcnt vmcnt(0)" ::: "memory");
      asm volatile("s_barrier" ::: "memory");
      if (kt + 2 < nkt) stage(kt + 2, (kt + 2) % 3);
      int cur = kt % 3;

      // S = Q K^T  (16 x 64)
      f32x4 sacc[4] = {};
      __builtin_amdgcn_s_setprio(1);
#pragma unroll
      for (int ks = 0; ks < 4; ++ks) {
#pragma unroll
        for (int ni = 0; ni < 4; ++ni) {
          int row = ni * 16 + (lane & 15);
          int cb = (ks * 64 + ((lane >> 4) << 4)) ^ ((row & 7) << 4);
          bf16x8 kf = *(const bf16x8*)((const char*)&Ks[cur][0] + row * 256 + cb);
          sacc[ni] = __builtin_amdgcn_mfma_f32_16x16x32_bf16(qf[ks], kf,
                                                             sacc[ni], 0, 0, 0);
        }
      }
      __builtin_amdgcn_s_setprio(0);

      // softmax in exp2 domain; defer max & sum (steady path: no cross-lane)
      bool diag = (kt >= 2 * qt);
      float sv[4][4];              // [ni][r]
      float pmax[4];
      bool allok = true;
#pragma unroll
      for (int r = 0; r < 4; ++r) {
        int qrow = qt * 128 + wid * 16 + ((lane >> 4) << 2) + r;
        float mx = -1e30f;
#pragma unroll
        for (int ni = 0; ni < 4; ++ni) {
          float s = sacc[ni][r] * SCL2;
          if (diag) {
            int kcol = kt * 64 + ni * 16 + (lane & 15);
            if (kcol > qrow) s = -1e30f;
          }
          sv[ni][r] = s;
          mx = fmaxf(mx, s);
        }
        pmax[r] = mx;
        allok = allok && (mx <= mrow[r] + 8.f);
      }
      if (!__all(allok)) {         // rare: running max moved -> reduce+rescale
#pragma unroll
        for (int r = 0; r < 4; ++r) {
          float gm = pmax[r];
          gm = fmaxf(gm, __shfl_xor(gm, 1));
          gm = fmaxf(gm, __shfl_xor(gm, 2));
          gm = fmaxf(gm, __shfl_xor(gm, 4));
          gm = fmaxf(gm, __shfl_xor(gm, 8));
          float mnew = fmaxf(mrow[r], gm);
          float fsc = exp2f(mrow[r] - mnew);
          mrow[r] = mnew;
          lrow[r] *= fsc;
#pragma unroll
          for (int nj = 0; nj < 8; ++nj) oacc[nj][r] *= fsc;
        }
      }

      // P = exp2(sv - m); per-lane partial sums; write P (bf16) to LDS
#pragma unroll
      for (int ni = 0; ni < 4; ++ni)
#pragma unroll
        for (int r = 0; r < 4; ++r) {
          float pp = exp2f(sv[ni][r] - mrow[r]);
          lrow[r] += pp;
          int row = ((lane >> 4) << 2) + r;
          int colb = (ni * 16 + (lane & 15)) * 2;
          *(unsigned short*)((char*)&Ps[wid][0] + row * 128 +
                             (colb ^ ((row & 7) << 4))) = f2bf(pp);
        }

      // O += P @ V  (same-wave LDS RAW; compiler inserts lgkmcnt waits)
      __builtin_amdgcn_s_setprio(1);
#pragma unroll
      for (int ks = 0; ks < 2; ++ks) {
        int prow = lane & 15;
        int pcb = (ks * 64 + ((lane >> 4) << 4)) ^ ((prow & 7) << 4);
        bf16x8 pf = *(const bf16x8*)((const char*)&Ps[wid][0] + prow * 128 + pcb);
#pragma unroll
        for (int nj = 0; nj < 8; ++nj) {
          int vrow = nj * 16 + (lane & 15);
          int vcb = (ks * 64 + ((lane >> 4) << 4)) ^ ((vrow & 7) << 4);
          bf16x8 vf = *(const bf16x8*)((const char*)&Vs[cur][0] + vrow * 128 + vcb);
          oacc[nj] = __builtin_amdgcn_mfma_f32_16x16x32_bf16(pf, vf,
                                                             oacc[nj], 0, 0, 0);
        }
      }
      __builtin_amdgcn_s_setprio(0);
    }

    // epilogue: reduce deferred row sums across 16-lane groups, normalize
    float inv[4];
#pragma unroll
    for (int r = 0; r < 4; ++r) {
      float s = lrow[r];
      s += __shfl_xor(s, 1);
      s += __shfl_xor(s, 2);
      s += __shfl_xor(s, 4);
      s += __shfl_xor(s, 8);
      inv[r] = 1.f / s;
    }
#pragma unroll
    for (int nj = 0; nj < 8; ++nj)
#pragma unroll
      for (int r = 0; r < 4; ++r) {
        int trow = qt * 128 + wid * 16 + ((lane >> 4) << 2) + r;
        int col = nj * 16 + (lane & 15);
        ao[((size_t)(b * Tc + trow)) * Dc + h * HD + col] =
            f2bf(oacc[nj][r] * inv[r]);
      }
  }
}

// ---------------- launcher --------------------------------------------------
extern "C" void kernel_launch(void* const* d_in, const int* in_sizes, int n_in,
                              void* d_out, int out_size, void* d_ws,
                              size_t ws_size, hipStream_t stream) {
  const float* x = (const float*)d_in[0];
  const float* w_qkv = (const float*)d_in[1];
  const float* w_out = (const float*)d_in[2];
  float* out = (float*)d_out;

  char* ws = (char*)d_ws;
  size_t off = 0;
  auto alloc = [&](size_t bytes) {
    char* p = ws + off;
    off += (bytes + 255) & ~(size_t)255;
    return p;
  };
  unsigned short* xb    = (unsigned short*)alloc((size_t)MR * Dc * 2);
  unsigned short* wqkvT = (unsigned short*)alloc((size_t)NQKV * Dc * 2);
  unsigned short* woutT = (unsigned short*)alloc((size_t)Dc * Dc * 2);
  unsigned short* qhp   = (unsigned short*)alloc((size_t)MR * Dc * 2);
  unsigned short* khp   = (unsigned short*)alloc((size_t)MR * Dc * 2);
  unsigned short* vtp   = (unsigned short*)alloc((size_t)MR * Dc * 2);
  unsigned short* aop   = (unsigned short*)alloc((size_t)MR * Dc * 2);
  float2* cs            = (float2*)alloc((size_t)Tc * 64 * sizeof(float2));

  rope_table_kernel<<<Tc, 64, 0, stream>>>(cs);
  f32_to_bf16_kernel<<<(MR * Dc / 4 + 255) / 256, 256, 0, stream>>>(x, xb, MR * Dc);
  transpose_f32_bf16_kernel<<<dim3(NQKV / 64, Dc / 64), 256, 0, stream>>>(
      w_qkv, wqkvT, Dc, NQKV);
  transpose_f32_bf16_kernel<<<dim3(Dc / 64, Dc / 64), 256, 0, stream>>>(
      w_out, woutT, Dc, Dc);
  gemm_qkv_kernel<<<(MR / 128) * (NQKV / 128), 256, 0, stream>>>(
      xb, wqkvT, cs, qhp, khp, vtp);
  attn_kernel<<<dim3(32, 8), 512, 0, stream>>>(qhp, khp, vtp, aop);
  gemm_bt_kernel<<<(MR / 128) * (Dc / 128), 256, 0, stream>>>(
      aop, woutT, out, MR, Dc, Dc);
}

// Round 12
// 248.026 us; speedup vs baseline: 1.0214x; 1.0214x over previous
//
#include <hip/hip_runtime.h>

typedef __attribute__((ext_vector_type(8))) short bf16x8;
typedef __attribute__((ext_vector_type(4))) float f32x4;

#define DEVICE __device__ __forceinline__

static constexpr int Tc = 2048;     // seq len
static constexpr int Dc = 2048;     // model dim
static constexpr int Hc = 16;       // heads
static constexpr int HD = 128;      // head dim
static constexpr int MR = 4096;     // B*T rows
static constexpr int NQKV = 6144;   // 3*D

DEVICE float bf2f(unsigned short u) {
  unsigned int t = ((unsigned int)u) << 16;
  float f; __builtin_memcpy(&f, &t, 4); return f;
}
DEVICE unsigned short f2bf(float f) {
  unsigned int t; __builtin_memcpy(&t, &f, 4);
  unsigned int r = (t + 0x7fffu + ((t >> 16) & 1u)) >> 16;
  return (unsigned short)r;
}

DEVICE void async_cp16(const void* g, void* lds) {
  __builtin_amdgcn_global_load_lds((const __attribute__((address_space(1))) void*)g,
                                   (__attribute__((address_space(3))) void*)lds, 16, 0, 0);
}

// epilogue LDS tile swizzle: row t (256B rows), byte col d2; bijective per row,
// spreads both row-major 16B reads and col-major scalar reads across banks.
DEVICE int lsw(int t, int d2) {
  return t * 256 + (d2 ^ ((((t & 7) ^ ((t >> 3) & 7)) << 4)));
}

// ---------------- RoPE cos/sin table: cs[t][j] = (cos, sin), j in [0,64) ----
__global__ void rope_table_kernel(float2* cs) {
  int t = blockIdx.x;
  int j = threadIdx.x;                   // 0..63
  float inv = powf(10000.0f, -(float)(2 * j) / 128.0f);
  float ang = (float)t * inv;
  cs[t * 64 + j] = make_float2(cosf(ang), sinf(ang));
}

// ---------------- fp32 -> bf16 elementwise (vectorized) ---------------------
__global__ void f32_to_bf16_kernel(const float* __restrict__ in,
                                   unsigned short* __restrict__ out, int n) {
  int i = (blockIdx.x * blockDim.x + threadIdx.x) * 4;
  if (i >= n) return;
  float4 v = *(const float4*)(in + i);
  ushort4 o;
  o.x = f2bf(v.x); o.y = f2bf(v.y); o.z = f2bf(v.z); o.w = f2bf(v.w);
  *(ushort4*)(out + i) = o;
}

// ------------- transpose fp32 (R x C) -> bf16 (C x R), 64x64 tiles ---------
// LDS stride 65 floats: write banks (r+4k+i)%32 2-way, read banks
// (8j+i+r)%32 2-way (both free; old [64][68] read phase was 8-way = 2.94x).
__global__ __launch_bounds__(256)
void transpose_f32_bf16_kernel(const float* __restrict__ in,
                               unsigned short* __restrict__ out,
                               int R, int C) {
  __shared__ float tile[64 * 65];
  int c0 = blockIdx.x * 64, r0 = blockIdx.y * 64;
  int tid = threadIdx.x;
#pragma unroll
  for (int it = 0; it < 4; ++it) {
    int idx = it * 256 + tid;        // 0..1023
    int r = idx >> 4;                // 0..63
    int c = (idx & 15) * 4;          // 0..60
    float4 v = *(const float4*)&in[(size_t)(r0 + r) * C + c0 + c];
    tile[r * 65 + c] = v.x; tile[r * 65 + c + 1] = v.y;
    tile[r * 65 + c + 2] = v.z; tile[r * 65 + c + 3] = v.w;
  }
  __syncthreads();
#pragma unroll
  for (int it = 0; it < 2; ++it) {
    int idx = it * 256 + tid;        // 0..511
    int r = idx >> 3;                // out row (c-dim) 0..63
    int c = (idx & 7) * 8;           // out col base (r-dim)
    bf16x8 ov;
#pragma unroll
    for (int i = 0; i < 8; ++i) ov[i] = (short)f2bf(tile[(c + i) * 65 + r]);
    *(bf16x8*)&out[(size_t)(c0 + r) * R + r0 + c] = ov;
  }
}

// ========== QKV GEMM with fused RoPE + head-split + V-transpose ============
// (round-10 proven single-buffer m97 structure + GROUP_M supertiling)
__global__ __launch_bounds__(256, 2)
void gemm_qkv_kernel(const unsigned short* __restrict__ A,
                     const unsigned short* __restrict__ Bt,
                     const float2* __restrict__ cs,
                     unsigned short* __restrict__ qh,
                     unsigned short* __restrict__ kh,
                     unsigned short* __restrict__ vt) {
  const int N = NQKV, K = Dc;
  __shared__ __align__(16) unsigned short sh[128 * 128];   // 32KB
  unsigned short* As = sh;               // [128*64] main-loop A tile
  unsigned short* Bs = sh + 128 * 64;    // [128*64] main-loop B tile

  int nbx = N >> 7;                      // 48
  int nwg = gridDim.x;                   // 1536
  int wg = blockIdx.x;
  int cpx = nwg >> 3;
  wg = (wg & 7) * cpx + (wg >> 3);       // XCD-contiguous (bijective: nwg%8==0)
  int gsize = nbx * 8;                   // GROUP_M=8 supertiles for L2 reuse
  int g = wg / gsize, rem = wg - g * gsize;
  int by = g * 8 + (rem & 7), bx = rem >> 3;
  int m0 = by << 7, n0 = bx << 7;

  int tid = threadIdx.x, lane = tid & 63, wid = tid >> 6;
  int wm = (wid >> 1) << 6, wn = (wid & 1) << 6;

  f32x4 acc[4][4] = {};

  for (int k0 = 0; k0 < K; k0 += 64) {
    __syncthreads();
#pragma unroll
    for (int r = 0; r < 4; ++r) {
      int p = r * 4096 + wid * 1024 + lane * 16;   // byte offset in tile
      int row = p >> 7;
      int cb = (p & 127) ^ ((row & 7) << 4);       // pre-swizzled source col
      const char* ga = (const char*)A + ((size_t)(m0 + row) * K + k0) * 2 + cb;
      async_cp16(ga, (char*)As + r * 4096 + wid * 1024);
      const char* gb = (const char*)Bt + ((size_t)(n0 + row) * K + k0) * 2 + cb;
      async_cp16(gb, (char*)Bs + r * 4096 + wid * 1024);
    }
    __syncthreads();

#pragma unroll
    for (int ks = 0; ks < 2; ++ks) {
      bf16x8 af[4], bfr[4];
#pragma unroll
      for (int mi = 0; mi < 4; ++mi) {
        int row = wm + mi * 16 + (lane & 15);
        int cb = (ks * 64 + ((lane >> 4) << 4)) ^ ((row & 7) << 4);
        af[mi] = *(const bf16x8*)((const char*)As + row * 128 + cb);
      }
#pragma unroll
      for (int ni = 0; ni < 4; ++ni) {
        int row = wn + ni * 16 + (lane & 15);
        int cb = (ks * 64 + ((lane >> 4) << 4)) ^ ((row & 7) << 4);
        bfr[ni] = *(const bf16x8*)((const char*)Bs + row * 128 + cb);
      }
#pragma unroll
      for (int mi = 0; mi < 4; ++mi)
#pragma unroll
        for (int ni = 0; ni < 4; ++ni)
          acc[mi][ni] = __builtin_amdgcn_mfma_f32_16x16x32_bf16(
              af[mi], bfr[ni], acc[mi][ni], 0, 0, 0);
    }
  }

  // ---- epilogue: acc -> LDS (bf16, swizzled) ----
  __syncthreads();   // all waves done reading As/Bs
#pragma unroll
  for (int mi = 0; mi < 4; ++mi)
#pragma unroll
    for (int ni = 0; ni < 4; ++ni)
#pragma unroll
      for (int r = 0; r < 4; ++r) {
        int t_ = wm + mi * 16 + ((lane >> 4) << 2) + r;
        int d_ = wn + ni * 16 + (lane & 15);
        *(unsigned short*)((char*)sh + lsw(t_, d_ * 2)) = f2bf(acc[mi][ni][r]);
      }
  __syncthreads();

  int sector = n0 >> 11;                 // 0=Q, 1=K, 2=V
  int h = (n0 & 2047) >> 7;
  if (sector < 2) {
    unsigned short* dst = sector ? kh : qh;
#pragma unroll
    for (int it = 0; it < 4; ++it) {
      int idx = it * 256 + tid;
      int r = idx >> 3, j0 = (idx & 7) * 8;
      int m = m0 + r;
      int t = m & (Tc - 1), b = m >> 11;
      bf16x8 o1, o2;
#pragma unroll
      for (int i = 0; i < 8; ++i) {
        float q1 = bf2f(*(const unsigned short*)((const char*)sh + lsw(r, (j0 + i) * 2)));
        float q2 = bf2f(*(const unsigned short*)((const char*)sh + lsw(r, (j0 + i + 64) * 2)));
        float2 c = cs[t * 64 + j0 + i];
        o1[i] = (short)f2bf(q1 * c.x - q2 * c.y);
        o2[i] = (short)f2bf(q2 * c.x + q1 * c.y);
      }
      size_t ob = ((size_t)(b * Hc + h) * Tc + t) * HD;
      *(bf16x8*)(dst + ob + j0) = o1;
      *(bf16x8*)(dst + ob + 64 + j0) = o2;
    }
  } else {
    int bh = (m0 >> 11) * Hc + h;
    int tb = m0 & (Tc - 1);
#pragma unroll
    for (int it = 0; it < 8; ++it) {
      int idx = it * 256 + tid;
      int d = idx >> 4, tc = idx & 15;
      bf16x8 o;
#pragma unroll
      for (int i = 0; i < 8; ++i)
        o[i] = (short)*(const unsigned short*)((const char*)sh + lsw(tc * 8 + i, d * 2));
      *(bf16x8*)(vt + (size_t)(bh * HD + d) * Tc + tb + tc * 8) = o;
    }
  }
}

// ---------------- 128x128 bf16 GEMM (m97 structure), for out-proj -----------
__global__ __launch_bounds__(256, 2)
void gemm_bt_kernel(const unsigned short* __restrict__ A,
                    const unsigned short* __restrict__ Bt,
                    float* __restrict__ C, int M, int N, int K) {
  __shared__ unsigned short As[128 * 64];
  __shared__ unsigned short Bs[128 * 64];

  int nbx = N >> 7;
  int nwg = gridDim.x;
  int wg = blockIdx.x;
  int cpx = nwg >> 3;
  wg = (wg & 7) * cpx + (wg >> 3);
  int gsize = nbx * 8;
  int g = wg / gsize, rem = wg - g * gsize;
  int by = g * 8 + (rem & 7), bx = rem >> 3;
  int m0 = by << 7, n0 = bx << 7;

  int tid = threadIdx.x, lane = tid & 63, wid = tid >> 6;
  int wm = (wid >> 1) << 6, wn = (wid & 1) << 6;

  f32x4 acc[4][4] = {};

  for (int k0 = 0; k0 < K; k0 += 64) {
    __syncthreads();
#pragma unroll
    for (int r = 0; r < 4; ++r) {
      int p = r * 4096 + wid * 1024 + lane * 16;
      int row = p >> 7;
      int cb = (p & 127) ^ ((row & 7) << 4);
      const char* ga = (const char*)A + ((size_t)(m0 + row) * K + k0) * 2 + cb;
      async_cp16(ga, (char*)As + r * 4096 + wid * 1024);
      const char* gb = (const char*)Bt + ((size_t)(n0 + row) * K + k0) * 2 + cb;
      async_cp16(gb, (char*)Bs + r * 4096 + wid * 1024);
    }
    __syncthreads();

#pragma unroll
    for (int ks = 0; ks < 2; ++ks) {
      bf16x8 af[4], bfr[4];
#pragma unroll
      for (int mi = 0; mi < 4; ++mi) {
        int row = wm + mi * 16 + (lane & 15);
        int cb = (ks * 64 + ((lane >> 4) << 4)) ^ ((row & 7) << 4);
        af[mi] = *(const bf16x8*)((const char*)As + row * 128 + cb);
      }
#pragma unroll
      for (int ni = 0; ni < 4; ++ni) {
        int row = wn + ni * 16 + (lane & 15);
        int cb = (ks * 64 + ((lane >> 4) << 4)) ^ ((row & 7) << 4);
        bfr[ni] = *(const bf16x8*)((const char*)Bs + row * 128 + cb);
      }
#pragma unroll
      for (int mi = 0; mi < 4; ++mi)
#pragma unroll
        for (int ni = 0; ni < 4; ++ni)
          acc[mi][ni] = __builtin_amdgcn_mfma_f32_16x16x32_bf16(
              af[mi], bfr[ni], acc[mi][ni], 0, 0, 0);
    }
  }

#pragma unroll
  for (int mi = 0; mi < 4; ++mi)
#pragma unroll
    for (int ni = 0; ni < 4; ++ni)
#pragma unroll
      for (int r = 0; r < 4; ++r) {
        int row = m0 + wm + mi * 16 + ((lane >> 4) << 2) + r;
        int col = n0 + wn + ni * 16 + (lane & 15);
        C[(size_t)row * N + col] = acc[mi][ni][r];
      }
}

// ---------------- causal flash attention (round-8 proven version) -----------
__global__ __launch_bounds__(512, 1)
void attn_kernel(const unsigned short* __restrict__ qh,
                 const unsigned short* __restrict__ kh,
                 const unsigned short* __restrict__ vt,
                 unsigned short* __restrict__ ao) {
  const float SCL2 = 0.08838834764831845f * 1.4426950408889634f;  // scale*log2e
  int bh = blockIdx.x;                       // 0..31
  int pairp = blockIdx.y;                    // 0..7
  int b = bh >> 4, h = bh & 15;

  __shared__ unsigned short Ks[3][64 * 128];   // 3 x 16KB, 256B rows, swizzled
  __shared__ unsigned short Vs[3][128 * 64];   // 3 x 16KB, V^T rows=d, 128B
  __shared__ unsigned short Ps[8][16 * 64];    // 16KB, per-wave P, 128B rows

  int tid = threadIdx.x, lane = tid & 63, wid = tid >> 6;

  const unsigned short* Kg = kh + (size_t)bh * Tc * HD;
  const unsigned short* Vg = vt + (size_t)bh * HD * Tc;

  auto stage = [&](int kt, int buf) {        // 4 vmem loads per thread
#pragma unroll
    for (int r = 0; r < 2; ++r) {
      int p = r * 8192 + wid * 1024 + lane * 16;
      {
        int row = p >> 8, cb = p & 255;
        const char* g = (const char*)Kg + ((size_t)(kt * 64 + row)) * 256 +
                        (cb ^ ((row & 7) << 4));
        async_cp16(g, (char*)&Ks[buf][0] + r * 8192 + wid * 1024);
      }
      {
        int d = p >> 7, cb = p & 127;
        const char* g = (const char*)Vg + (size_t)d * (Tc * 2) + kt * 128 +
                        (cb ^ ((d & 7) << 4));
        async_cp16(g, (char*)&Vs[buf][0] + r * 8192 + wid * 1024);
      }
    }
  };

#pragma unroll 1
  for (int pass = 0; pass < 2; ++pass) {
    int qt = pass ? (15 - pairp) : pairp;
    const unsigned short* Qg = qh + ((size_t)bh * Tc + qt * 128) * HD;

    // Q fragments direct from global; drain so loop vmcnt counts stay exact
    bf16x8 qf[4];
#pragma unroll
    for (int ks = 0; ks < 4; ++ks) {
      int row = wid * 16 + (lane & 15);
      qf[ks] = *(const bf16x8*)((const char*)Qg + row * 256 + ks * 64 +
                                ((lane >> 4) << 4));
    }
    asm volatile("s_waitcnt vmcnt(0)" ::: "memory");

    f32x4 oacc[8] = {};
    float mrow[4], lrow[4];
#pragma unroll
    for (int r = 0; r < 4; ++r) { mrow[r] = -1e30f; lrow[r] = 0.f; }

    int nkt = 2 * (qt + 1);
    __syncthreads();     // pass boundary: prior pass's LDS reads done
    stage(0, 0);
    stage(1, 1);         // nkt >= 2 always
#pragma unroll 1
    for (int kt = 0; kt < nkt; ++kt) {
      // wait for tile kt (own loads), then barrier -> all threads' loads done
      if (kt + 1 < nkt)
        asm volatile("s_waitcnt vmcnt(4)" ::: "memory");
      else
        asm volatile("s_waitcnt vmcnt(0)" ::: "memory");
      asm volatile("s_barrier" ::: "memory");
      if (kt + 2 < nkt) stage(kt + 2, (kt + 2) % 3);
      int cur = kt % 3;

      // S = Q K^T  (16 x 64)
      f32x4 sacc[4] = {};
      __builtin_amdgcn_s_setprio(1);
#pragma unroll
      for (int ks = 0; ks < 4; ++ks) {
#pragma unroll
        for (int ni = 0; ni < 4; ++ni) {
          int row = ni * 16 + (lane & 15);
          int cb = (ks * 64 + ((lane >> 4) << 4)) ^ ((row & 7) << 4);
          bf16x8 kf = *(const bf16x8*)((const char*)&Ks[cur][0] + row * 256 + cb);
          sacc[ni] = __builtin_amdgcn_mfma_f32_16x16x32_bf16(qf[ks], kf,
                                                             sacc[ni], 0, 0, 0);
        }
      }
      __builtin_amdgcn_s_setprio(0);

      // softmax in exp2 domain; defer max & sum (steady path: no cross-lane)
      bool diag = (kt >= 2 * qt);
      float sv[4][4];              // [ni][r]
      float pmax[4];
      bool allok = true;
#pragma unroll
      for (int r = 0; r < 4; ++r) {
        int qrow = qt * 128 + wid * 16 + ((lane >> 4) << 2) + r;
        float mx = -1e30f;
#pragma unroll
        for (int ni = 0; ni < 4; ++ni) {
          float s = sacc[ni][r] * SCL2;
          if (diag) {
            int kcol = kt * 64 + ni * 16 + (lane & 15);
            if (kcol > qrow) s = -1e30f;
          }
          sv[ni][r] = s;
          mx = fmaxf(mx, s);
        }
        pmax[r] = mx;
        allok = allok && (mx <= mrow[r] + 8.f);
      }
      if (!__all(allok)) {         // rare: running max moved -> reduce+rescale
#pragma unroll
        for (int r = 0; r < 4; ++r) {
          float gm = pmax[r];
          gm = fmaxf(gm, __shfl_xor(gm, 1));
          gm = fmaxf(gm, __shfl_xor(gm, 2));
          gm = fmaxf(gm, __shfl_xor(gm, 4));
          gm = fmaxf(gm, __shfl_xor(gm, 8));
          float mnew = fmaxf(mrow[r], gm);
          float fsc = exp2f(mrow[r] - mnew);
          mrow[r] = mnew;
          lrow[r] *= fsc;
#pragma unroll
          for (int nj = 0; nj < 8; ++nj) oacc[nj][r] *= fsc;
        }
      }

      // P = exp2(sv - m); per-lane partial sums; write P (bf16) to LDS
#pragma unroll
      for (int ni = 0; ni < 4; ++ni)
#pragma unroll
        for (int r = 0; r < 4; ++r) {
          float pp = exp2f(sv[ni][r] - mrow[r]);
          lrow[r] += pp;
          int row = ((lane >> 4) << 2) + r;
          int colb = (ni * 16 + (lane & 15)) * 2;
          *(unsigned short*)((char*)&Ps[wid][0] + row * 128 +
                             (colb ^ ((row & 7) << 4))) = f2bf(pp);
        }

      // O += P @ V  (same-wave LDS RAW; compiler inserts lgkmcnt waits)
      __builtin_amdgcn_s_setprio(1);
#pragma unroll
      for (int ks = 0; ks < 2; ++ks) {
        int prow = lane & 15;
        int pcb = (ks * 64 + ((lane >> 4) << 4)) ^ ((prow & 7) << 4);
        bf16x8 pf = *(const bf16x8*)((const char*)&Ps[wid][0] + prow * 128 + pcb);
#pragma unroll
        for (int nj = 0; nj < 8; ++nj) {
          int vrow = nj * 16 + (lane & 15);
          int vcb = (ks * 64 + ((lane >> 4) << 4)) ^ ((vrow & 7) << 4);
          bf16x8 vf = *(const bf16x8*)((const char*)&Vs[cur][0] + vrow * 128 + vcb);
          oacc[nj] = __builtin_amdgcn_mfma_f32_16x16x32_bf16(pf, vf,
                                                             oacc[nj], 0, 0, 0);
        }
      }
      __builtin_amdgcn_s_setprio(0);
    }

    // epilogue: reduce deferred row sums across 16-lane groups, normalize
    float inv[4];
#pragma unroll
    for (int r = 0; r < 4; ++r) {
      float s = lrow[r];
      s += __shfl_xor(s, 1);
      s += __shfl_xor(s, 2);
      s += __shfl_xor(s, 4);
      s += __shfl_xor(s, 8);
      inv[r] = 1.f / s;
    }
#pragma unroll
    for (int nj = 0; nj < 8; ++nj)
#pragma unroll
      for (int r = 0; r < 4; ++r) {
        int trow = qt * 128 + wid * 16 + ((lane >> 4) << 2) + r;
        int col = nj * 16 + (lane & 15);
        ao[((size_t)(b * Tc + trow)) * Dc + h * HD + col] =
            f2bf(oacc[nj][r] * inv[r]);
      }
  }
}

// ---------------- launcher --------------------------------------------------
extern "C" void kernel_launch(void* const* d_in, const int* in_sizes, int n_in,
                              void* d_out, int out_size, void* d_ws,
                              size_t ws_size, hipStream_t stream) {
  const float* x = (const float*)d_in[0];
  const float* w_qkv = (const float*)d_in[1];
  const float* w_out = (const float*)d_in[2];
  float* out = (float*)d_out;

  char* ws = (char*)d_ws;
  size_t off = 0;
  auto alloc = [&](size_t bytes) {
    char* p = ws + off;
    off += (bytes + 255) & ~(size_t)255;
    return p;
  };
  unsigned short* xb    = (unsigned short*)alloc((size_t)MR * Dc * 2);
  unsigned short* wqkvT = (unsigned short*)alloc((size_t)NQKV * Dc * 2);
  unsigned short* woutT = (unsigned short*)alloc((size_t)Dc * Dc * 2);
  unsigned short* qhp   = (unsigned short*)alloc((size_t)MR * Dc * 2);
  unsigned short* khp   = (unsigned short*)alloc((size_t)MR * Dc * 2);
  unsigned short* vtp   = (unsigned short*)alloc((size_t)MR * Dc * 2);
  unsigned short* aop   = (unsigned short*)alloc((size_t)MR * Dc * 2);
  float2* cs            = (float2*)alloc((size_t)Tc * 64 * sizeof(float2));

  rope_table_kernel<<<Tc, 64, 0, stream>>>(cs);
  f32_to_bf16_kernel<<<(MR * Dc / 4 + 255) / 256, 256, 0, stream>>>(x, xb, MR * Dc);
  transpose_f32_bf16_kernel<<<dim3(NQKV / 64, Dc / 64), 256, 0, stream>>>(
      w_qkv, wqkvT, Dc, NQKV);
  transpose_f32_bf16_kernel<<<dim3(Dc / 64, Dc / 64), 256, 0, stream>>>(
      w_out, woutT, Dc, Dc);
  gemm_qkv_kernel<<<(MR / 128) * (NQKV / 128), 256, 0, stream>>>(
      xb, wqkvT, cs, qhp, khp, vtp);
  attn_kernel<<<dim3(32, 8), 512, 0, stream>>>(qhp, khp, vtp, aop);
  gemm_bt_kernel<<<(MR / 128) * (Dc / 128), 256, 0, stream>>>(
      aop, woutT, out, MR, Dc, Dc);
}

// Round 13
// 242.542 us; speedup vs baseline: 1.0445x; 1.0226x over previous
//
#include <hip/hip_runtime.h>

typedef __attribute__((ext_vector_type(8))) short bf16x8;
typedef __attribute__((ext_vector_type(4))) float f32x4;

#define DEVICE __device__ __forceinline__

static constexpr int Tc = 2048;     // seq len
static constexpr int Dc = 2048;     // model dim
static constexpr int Hc = 16;       // heads
static constexpr int HD = 128;      // head dim
static constexpr int MR = 4096;     // B*T rows
static constexpr int NQKV = 6144;   // 3*D

DEVICE float bf2f(unsigned short u) {
  unsigned int t = ((unsigned int)u) << 16;
  float f; __builtin_memcpy(&f, &t, 4); return f;
}
DEVICE unsigned short f2bf(float f) {
  unsigned int t; __builtin_memcpy(&t, &f, 4);
  unsigned int r = (t + 0x7fffu + ((t >> 16) & 1u)) >> 16;
  return (unsigned short)r;
}

DEVICE void async_cp16(const void* g, void* lds) {
  __builtin_amdgcn_global_load_lds((const __attribute__((address_space(1))) void*)g,
                                   (__attribute__((address_space(3))) void*)lds, 16, 0, 0);
}

// epilogue LDS tile swizzle: row t (256B rows), byte col d2; bijective per row,
// spreads both row-major 16B reads and col-major scalar reads across banks.
DEVICE int lsw(int t, int d2) {
  return t * 256 + (d2 ^ ((((t & 7) ^ ((t >> 3) & 7)) << 4)));
}

// -------- fused prep: fp32->bf16 convert (8/thread) + RoPE cos/sin table ----
// blocks [0, 4096): convert x (8.4M f32); blocks [4096, 4608): cs table rows.
__global__ __launch_bounds__(256)
void prep_kernel(const float* __restrict__ in, unsigned short* __restrict__ out,
                 float2* __restrict__ cs) {
  int tid = threadIdx.x;
  if (blockIdx.x < 4096) {
    int i = (blockIdx.x * 256 + tid) * 8;
    float4 v0 = *(const float4*)(in + i);
    float4 v1 = *(const float4*)(in + i + 4);
    bf16x8 o;
    o[0] = (short)f2bf(v0.x); o[1] = (short)f2bf(v0.y);
    o[2] = (short)f2bf(v0.z); o[3] = (short)f2bf(v0.w);
    o[4] = (short)f2bf(v1.x); o[5] = (short)f2bf(v1.y);
    o[6] = (short)f2bf(v1.z); o[7] = (short)f2bf(v1.w);
    *(bf16x8*)(out + i) = o;
  } else {
    int t = (blockIdx.x - 4096) * 4 + (tid >> 6);   // 0..2047
    int j = tid & 63;
    // inv = 10000^(-j/64) = exp2(-j * log2(10000)/64)
    float inv = exp2f(-(float)j * 0.20764137662f);
    float ang = (float)t * inv;
    cs[t * 64 + j] = make_float2(cosf(ang), sinf(ang));
  }
}

// ------------- transpose fp32 (R x C) -> bf16 (C x R), 64x64 tiles ---------
// LDS stride 65 floats: write banks 2-way, read banks 2-way (both free).
__global__ __launch_bounds__(256)
void transpose_f32_bf16_kernel(const float* __restrict__ in,
                               unsigned short* __restrict__ out,
                               int R, int C) {
  __shared__ float tile[64 * 65];
  int c0 = blockIdx.x * 64, r0 = blockIdx.y * 64;
  int tid = threadIdx.x;
#pragma unroll
  for (int it = 0; it < 4; ++it) {
    int idx = it * 256 + tid;        // 0..1023
    int r = idx >> 4;                // 0..63
    int c = (idx & 15) * 4;          // 0..60
    float4 v = *(const float4*)&in[(size_t)(r0 + r) * C + c0 + c];
    tile[r * 65 + c] = v.x; tile[r * 65 + c + 1] = v.y;
    tile[r * 65 + c + 2] = v.z; tile[r * 65 + c + 3] = v.w;
  }
  __syncthreads();
#pragma unroll
  for (int it = 0; it < 2; ++it) {
    int idx = it * 256 + tid;        // 0..511
    int r = idx >> 3;                // out row (c-dim) 0..63
    int c = (idx & 7) * 8;           // out col base (r-dim)
    bf16x8 ov;
#pragma unroll
    for (int i = 0; i < 8; ++i) ov[i] = (short)f2bf(tile[(c + i) * 65 + r]);
    *(bf16x8*)&out[(size_t)(c0 + r) * R + r0 + c] = ov;
  }
}

// ========== QKV GEMM with fused RoPE + head-split + V-transpose ============
// (proven single-buffer m97 structure + GROUP_M supertiling)
__global__ __launch_bounds__(256, 2)
void gemm_qkv_kernel(const unsigned short* __restrict__ A,
                     const unsigned short* __restrict__ Bt,
                     const float2* __restrict__ cs,
                     unsigned short* __restrict__ qh,
                     unsigned short* __restrict__ kh,
                     unsigned short* __restrict__ vt) {
  const int N = NQKV, K = Dc;
  __shared__ __align__(16) unsigned short sh[128 * 128];   // 32KB
  unsigned short* As = sh;               // [128*64] main-loop A tile
  unsigned short* Bs = sh + 128 * 64;    // [128*64] main-loop B tile

  int nbx = N >> 7;                      // 48
  int nwg = gridDim.x;                   // 1536
  int wg = blockIdx.x;
  int cpx = nwg >> 3;
  wg = (wg & 7) * cpx + (wg >> 3);       // XCD-contiguous (bijective: nwg%8==0)
  int gsize = nbx * 8;                   // GROUP_M=8 supertiles for L2 reuse
  int g = wg / gsize, rem = wg - g * gsize;
  int by = g * 8 + (rem & 7), bx = rem >> 3;
  int m0 = by << 7, n0 = bx << 7;

  int tid = threadIdx.x, lane = tid & 63, wid = tid >> 6;
  int wm = (wid >> 1) << 6, wn = (wid & 1) << 6;

  f32x4 acc[4][4] = {};

  for (int k0 = 0; k0 < K; k0 += 64) {
    __syncthreads();
#pragma unroll
    for (int r = 0; r < 4; ++r) {
      int p = r * 4096 + wid * 1024 + lane * 16;   // byte offset in tile
      int row = p >> 7;
      int cb = (p & 127) ^ ((row & 7) << 4);       // pre-swizzled source col
      const char* ga = (const char*)A + ((size_t)(m0 + row) * K + k0) * 2 + cb;
      async_cp16(ga, (char*)As + r * 4096 + wid * 1024);
      const char* gb = (const char*)Bt + ((size_t)(n0 + row) * K + k0) * 2 + cb;
      async_cp16(gb, (char*)Bs + r * 4096 + wid * 1024);
    }
    __syncthreads();

#pragma unroll
    for (int ks = 0; ks < 2; ++ks) {
      bf16x8 af[4], bfr[4];
#pragma unroll
      for (int mi = 0; mi < 4; ++mi) {
        int row = wm + mi * 16 + (lane & 15);
        int cb = (ks * 64 + ((lane >> 4) << 4)) ^ ((row & 7) << 4);
        af[mi] = *(const bf16x8*)((const char*)As + row * 128 + cb);
      }
#pragma unroll
      for (int ni = 0; ni < 4; ++ni) {
        int row = wn + ni * 16 + (lane & 15);
        int cb = (ks * 64 + ((lane >> 4) << 4)) ^ ((row & 7) << 4);
        bfr[ni] = *(const bf16x8*)((const char*)Bs + row * 128 + cb);
      }
#pragma unroll
      for (int mi = 0; mi < 4; ++mi)
#pragma unroll
        for (int ni = 0; ni < 4; ++ni)
          acc[mi][ni] = __builtin_amdgcn_mfma_f32_16x16x32_bf16(
              af[mi], bfr[ni], acc[mi][ni], 0, 0, 0);
    }
  }

  // ---- epilogue: acc -> LDS (bf16, swizzled) ----
  __syncthreads();   // all waves done reading As/Bs
#pragma unroll
  for (int mi = 0; mi < 4; ++mi)
#pragma unroll
    for (int ni = 0; ni < 4; ++ni)
#pragma unroll
      for (int r = 0; r < 4; ++r) {
        int t_ = wm + mi * 16 + ((lane >> 4) << 2) + r;
        int d_ = wn + ni * 16 + (lane & 15);
        *(unsigned short*)((char*)sh + lsw(t_, d_ * 2)) = f2bf(acc[mi][ni][r]);
      }
  __syncthreads();

  int sector = n0 >> 11;                 // 0=Q, 1=K, 2=V
  int h = (n0 & 2047) >> 7;
  if (sector < 2) {
    unsigned short* dst = sector ? kh : qh;
#pragma unroll
    for (int it = 0; it < 4; ++it) {
      int idx = it * 256 + tid;
      int r = idx >> 3, j0 = (idx & 7) * 8;
      int m = m0 + r;
      int t = m & (Tc - 1), b = m >> 11;
      bf16x8 o1, o2;
#pragma unroll
      for (int i = 0; i < 8; ++i) {
        float q1 = bf2f(*(const unsigned short*)((const char*)sh + lsw(r, (j0 + i) * 2)));
        float q2 = bf2f(*(const unsigned short*)((const char*)sh + lsw(r, (j0 + i + 64) * 2)));
        float2 c = cs[t * 64 + j0 + i];
        o1[i] = (short)f2bf(q1 * c.x - q2 * c.y);
        o2[i] = (short)f2bf(q2 * c.x + q1 * c.y);
      }
      size_t ob = ((size_t)(b * Hc + h) * Tc + t) * HD;
      *(bf16x8*)(dst + ob + j0) = o1;
      *(bf16x8*)(dst + ob + 64 + j0) = o2;
    }
  } else {
    int bh = (m0 >> 11) * Hc + h;
    int tb = m0 & (Tc - 1);
#pragma unroll
    for (int it = 0; it < 8; ++it) {
      int idx = it * 256 + tid;
      int d = idx >> 4, tc = idx & 15;
      bf16x8 o;
#pragma unroll
      for (int i = 0; i < 8; ++i)
        o[i] = (short)*(const unsigned short*)((const char*)sh + lsw(tc * 8 + i, d * 2));
      *(bf16x8*)(vt + (size_t)(bh * HD + d) * Tc + tb + tc * 8) = o;
    }
  }
}

// ---------------- 128x128 bf16 GEMM (m97 structure), for out-proj -----------
__global__ __launch_bounds__(256, 2)
void gemm_bt_kernel(const unsigned short* __restrict__ A,
                    const unsigned short* __restrict__ Bt,
                    float* __restrict__ C, int M, int N, int K) {
  __shared__ unsigned short As[128 * 64];
  __shared__ unsigned short Bs[128 * 64];

  int nbx = N >> 7;
  int nwg = gridDim.x;
  int wg = blockIdx.x;
  int cpx = nwg >> 3;
  wg = (wg & 7) * cpx + (wg >> 3);
  int gsize = nbx * 8;
  int g = wg / gsize, rem = wg - g * gsize;
  int by = g * 8 + (rem & 7), bx = rem >> 3;
  int m0 = by << 7, n0 = bx << 7;

  int tid = threadIdx.x, lane = tid & 63, wid = tid >> 6;
  int wm = (wid >> 1) << 6, wn = (wid & 1) << 6;

  f32x4 acc[4][4] = {};

  for (int k0 = 0; k0 < K; k0 += 64) {
    __syncthreads();
#pragma unroll
    for (int r = 0; r < 4; ++r) {
      int p = r * 4096 + wid * 1024 + lane * 16;
      int row = p >> 7;
      int cb = (p & 127) ^ ((row & 7) << 4);
      const char* ga = (const char*)A + ((size_t)(m0 + row) * K + k0) * 2 + cb;
      async_cp16(ga, (char*)As + r * 4096 + wid * 1024);
      const char* gb = (const char*)Bt + ((size_t)(n0 + row) * K + k0) * 2 + cb;
      async_cp16(gb, (char*)Bs + r * 4096 + wid * 1024);
    }
    __syncthreads();

#pragma unroll
    for (int ks = 0; ks < 2; ++ks) {
      bf16x8 af[4], bfr[4];
#pragma unroll
      for (int mi = 0; mi < 4; ++mi) {
        int row = wm + mi * 16 + (lane & 15);
        int cb = (ks * 64 + ((lane >> 4) << 4)) ^ ((row & 7) << 4);
        af[mi] = *(const bf16x8*)((const char*)As + row * 128 + cb);
      }
#pragma unroll
      for (int ni = 0; ni < 4; ++ni) {
        int row = wn + ni * 16 + (lane & 15);
        int cb = (ks * 64 + ((lane >> 4) << 4)) ^ ((row & 7) << 4);
        bfr[ni] = *(const bf16x8*)((const char*)Bs + row * 128 + cb);
      }
#pragma unroll
      for (int mi = 0; mi < 4; ++mi)
#pragma unroll
        for (int ni = 0; ni < 4; ++ni)
          acc[mi][ni] = __builtin_amdgcn_mfma_f32_16x16x32_bf16(
              af[mi], bfr[ni], acc[mi][ni], 0, 0, 0);
    }
  }

#pragma unroll
  for (int mi = 0; mi < 4; ++mi)
#pragma unroll
    for (int ni = 0; ni < 4; ++ni)
#pragma unroll
      for (int r = 0; r < 4; ++r) {
        int row = m0 + wm + mi * 16 + ((lane >> 4) << 2) + r;
        int col = n0 + wn + ni * 16 + (lane & 15);
        C[(size_t)row * N + col] = acc[mi][ni][r];
      }
}

// ---------------- causal flash attention (round-8 proven version) -----------
__global__ __launch_bounds__(512, 1)
void attn_kernel(const unsigned short* __restrict__ qh,
                 const unsigned short* __restrict__ kh,
                 const unsigned short* __restrict__ vt,
                 unsigned short* __restrict__ ao) {
  const float SCL2 = 0.08838834764831845f * 1.4426950408889634f;  // scale*log2e
  int bh = blockIdx.x;                       // 0..31
  int pairp = blockIdx.y;                    // 0..7
  int b = bh >> 4, h = bh & 15;

  __shared__ unsigned short Ks[3][64 * 128];   // 3 x 16KB, 256B rows, swizzled
  __shared__ unsigned short Vs[3][128 * 64];   // 3 x 16KB, V^T rows=d, 128B
  __shared__ unsigned short Ps[8][16 * 64];    // 16KB, per-wave P, 128B rows

  int tid = threadIdx.x, lane = tid & 63, wid = tid >> 6;

  const unsigned short* Kg = kh + (size_t)bh * Tc * HD;
  const unsigned short* Vg = vt + (size_t)bh * HD * Tc;

  auto stage = [&](int kt, int buf) {        // 4 vmem loads per thread
#pragma unroll
    for (int r = 0; r < 2; ++r) {
      int p = r * 8192 + wid * 1024 + lane * 16;
      {
        int row = p >> 8, cb = p & 255;
        const char* g = (const char*)Kg + ((size_t)(kt * 64 + row)) * 256 +
                        (cb ^ ((row & 7) << 4));
        async_cp16(g, (char*)&Ks[buf][0] + r * 8192 + wid * 1024);
      }
      {
        int d = p >> 7, cb = p & 127;
        const char* g = (const char*)Vg + (size_t)d * (Tc * 2) + kt * 128 +
                        (cb ^ ((d & 7) << 4));
        async_cp16(g, (char*)&Vs[buf][0] + r * 8192 + wid * 1024);
      }
    }
  };

#pragma unroll 1
  for (int pass = 0; pass < 2; ++pass) {
    int qt = pass ? (15 - pairp) : pairp;
    const unsigned short* Qg = qh + ((size_t)bh * Tc + qt * 128) * HD;

    // Q fragments direct from global; drain so loop vmcnt counts stay exact
    bf16x8 qf[4];
#pragma unroll
    for (int ks = 0; ks < 4; ++ks) {
      int row = wid * 16 + (lane & 15);
      qf[ks] = *(const bf16x8*)((const char*)Qg + row * 256 + ks * 64 +
                                ((lane >> 4) << 4));
    }
    asm volatile("s_waitcnt vmcnt(0)" ::: "memory");

    f32x4 oacc[8] = {};
    float mrow[4], lrow[4];
#pragma unroll
    for (int r = 0; r < 4; ++r) { mrow[r] = -1e30f; lrow[r] = 0.f; }

    int nkt = 2 * (qt + 1);
    __syncthreads();     // pass boundary: prior pass's LDS reads done
    stage(0, 0);
    stage(1, 1);         // nkt >= 2 always
#pragma unroll 1
    for (int kt = 0; kt < nkt; ++kt) {
      // wait for tile kt (own loads), then barrier -> all threads' loads done
      if (kt + 1 < nkt)
        asm volatile("s_waitcnt vmcnt(4)" ::: "memory");
      else
        asm volatile("s_waitcnt vmcnt(0)" ::: "memory");
      asm volatile("s_barrier" ::: "memory");
      if (kt + 2 < nkt) stage(kt + 2, (kt + 2) % 3);
      int cur = kt % 3;

      // S = Q K^T  (16 x 64)
      f32x4 sacc[4] = {};
      __builtin_amdgcn_s_setprio(1);
#pragma unroll
      for (int ks = 0; ks < 4; ++ks) {
#pragma unroll
        for (int ni = 0; ni < 4; ++ni) {
          int row = ni * 16 + (lane & 15);
          int cb = (ks * 64 + ((lane >> 4) << 4)) ^ ((row & 7) << 4);
          bf16x8 kf = *(const bf16x8*)((const char*)&Ks[cur][0] + row * 256 + cb);
          sacc[ni] = __builtin_amdgcn_mfma_f32_16x16x32_bf16(qf[ks], kf,
                                                             sacc[ni], 0, 0, 0);
        }
      }
      __builtin_amdgcn_s_setprio(0);

      // softmax in exp2 domain; defer max & sum (steady path: no cross-lane)
      bool diag = (kt >= 2 * qt);
      float sv[4][4];              // [ni][r]
      float pmax[4];
      bool allok = true;
#pragma unroll
      for (int r = 0; r < 4; ++r) {
        int qrow = qt * 128 + wid * 16 + ((lane >> 4) << 2) + r;
        float mx = -1e30f;
#pragma unroll
        for (int ni = 0; ni < 4; ++ni) {
          float s = sacc[ni][r] * SCL2;
          if (diag) {
            int kcol = kt * 64 + ni * 16 + (lane & 15);
            if (kcol > qrow) s = -1e30f;
          }
          sv[ni][r] = s;
          mx = fmaxf(mx, s);
        }
        pmax[r] = mx;
        allok = allok && (mx <= mrow[r] + 8.f);
      }
      if (!__all(allok)) {         // rare: running max moved -> reduce+rescale
#pragma unroll
        for (int r = 0; r < 4; ++r) {
          float gm = pmax[r];
          gm = fmaxf(gm, __shfl_xor(gm, 1));
          gm = fmaxf(gm, __shfl_xor(gm, 2));
          gm = fmaxf(gm, __shfl_xor(gm, 4));
          gm = fmaxf(gm, __shfl_xor(gm, 8));
          float mnew = fmaxf(mrow[r], gm);
          float fsc = exp2f(mrow[r] - mnew);
          mrow[r] = mnew;
          lrow[r] *= fsc;
#pragma unroll
          for (int nj = 0; nj < 8; ++nj) oacc[nj][r] *= fsc;
        }
      }

      // P = exp2(sv - m); per-lane partial sums; write P (bf16) to LDS
#pragma unroll
      for (int ni = 0; ni < 4; ++ni)
#pragma unroll
        for (int r = 0; r < 4; ++r) {
          float pp = exp2f(sv[ni][r] - mrow[r]);
          lrow[r] += pp;
          int row = ((lane >> 4) << 2) + r;
          int colb = (ni * 16 + (lane & 15)) * 2;
          *(unsigned short*)((char*)&Ps[wid][0] + row * 128 +
                             (colb ^ ((row & 7) << 4))) = f2bf(pp);
        }

      // O += P @ V  (same-wave LDS RAW; compiler inserts lgkmcnt waits)
      __builtin_amdgcn_s_setprio(1);
#pragma unroll
      for (int ks = 0; ks < 2; ++ks) {
        int prow = lane & 15;
        int pcb = (ks * 64 + ((lane >> 4) << 4)) ^ ((prow & 7) << 4);
        bf16x8 pf = *(const bf16x8*)((const char*)&Ps[wid][0] + prow * 128 + pcb);
#pragma unroll
        for (int nj = 0; nj < 8; ++nj) {
          int vrow = nj * 16 + (lane & 15);
          int vcb = (ks * 64 + ((lane >> 4) << 4)) ^ ((vrow & 7) << 4);
          bf16x8 vf = *(const bf16x8*)((const char*)&Vs[cur][0] + vrow * 128 + vcb);
          oacc[nj] = __builtin_amdgcn_mfma_f32_16x16x32_bf16(pf, vf,
                                                             oacc[nj], 0, 0, 0);
        }
      }
      __builtin_amdgcn_s_setprio(0);
    }

    // epilogue: reduce deferred row sums across 16-lane groups, normalize
    float inv[4];
#pragma unroll
    for (int r = 0; r < 4; ++r) {
      float s = lrow[r];
      s += __shfl_xor(s, 1);
      s += __shfl_xor(s, 2);
      s += __shfl_xor(s, 4);
      s += __shfl_xor(s, 8);
      inv[r] = 1.f / s;
    }
#pragma unroll
    for (int nj = 0; nj < 8; ++nj)
#pragma unroll
      for (int r = 0; r < 4; ++r) {
        int trow = qt * 128 + wid * 16 + ((lane >> 4) << 2) + r;
        int col = nj * 16 + (lane & 15);
        ao[((size_t)(b * Tc + trow)) * Dc + h * HD + col] =
            f2bf(oacc[nj][r] * inv[r]);
      }
  }
}

// ---------------- launcher --------------------------------------------------
extern "C" void kernel_launch(void* const* d_in, const int* in_sizes, int n_in,
                              void* d_out, int out_size, void* d_ws,
                              size_t ws_size, hipStream_t stream) {
  const float* x = (const float*)d_in[0];
  const float* w_qkv = (const float*)d_in[1];
  const float* w_out = (const float*)d_in[2];
  float* out = (float*)d_out;

  char* ws = (char*)d_ws;
  size_t off = 0;
  auto alloc = [&](size_t bytes) {
    char* p = ws + off;
    off += (bytes + 255) & ~(size_t)255;
    return p;
  };
  unsigned short* xb    = (unsigned short*)alloc((size_t)MR * Dc * 2);
  unsigned short* wqkvT = (unsigned short*)alloc((size_t)NQKV * Dc * 2);
  unsigned short* woutT = (unsigned short*)alloc((size_t)Dc * Dc * 2);
  unsigned short* qhp   = (unsigned short*)alloc((size_t)MR * Dc * 2);
  unsigned short* khp   = (unsigned short*)alloc((size_t)MR * Dc * 2);
  unsigned short* vtp   = (unsigned short*)alloc((size_t)MR * Dc * 2);
  unsigned short* aop   = (unsigned short*)alloc((size_t)MR * Dc * 2);
  float2* cs            = (float2*)alloc((size_t)Tc * 64 * sizeof(float2));

  prep_kernel<<<4096 + 512, 256, 0, stream>>>(x, xb, cs);
  transpose_f32_bf16_kernel<<<dim3(NQKV / 64, Dc / 64), 256, 0, stream>>>(
      w_qkv, wqkvT, Dc, NQKV);
  transpose_f32_bf16_kernel<<<dim3(Dc / 64, Dc / 64), 256, 0, stream>>>(
      w_out, woutT, Dc, Dc);
  gemm_qkv_kernel<<<(MR / 128) * (NQKV / 128), 256, 0, stream>>>(
      xb, wqkvT, cs, qhp, khp, vtp);
  attn_kernel<<<dim3(32, 8), 512, 0, stream>>>(qhp, khp, vtp, aop);
  gemm_bt_kernel<<<(MR / 128) * (Dc / 128), 256, 0, stream>>>(
      aop, woutT, out, MR, Dc, Dc);
}

// Round 14
// 240.588 us; speedup vs baseline: 1.0529x; 1.0081x over previous
//
#include <hip/hip_runtime.h>

typedef __attribute__((ext_vector_type(8))) short bf16x8;
typedef __attribute__((ext_vector_type(4))) float f32x4;

#define DEVICE __device__ __forceinline__

static constexpr int Tc = 2048;     // seq len
static constexpr int Dc = 2048;     // model dim
static constexpr int Hc = 16;       // heads
static constexpr int HD = 128;      // head dim
static constexpr int MR = 4096;     // B*T rows
static constexpr int NQKV = 6144;   // 3*D

DEVICE float bf2f(unsigned short u) {
  unsigned int t = ((unsigned int)u) << 16;
  float f; __builtin_memcpy(&f, &t, 4); return f;
}
DEVICE unsigned short f2bf(float f) {
  unsigned int t; __builtin_memcpy(&t, &f, 4);
  unsigned int r = (t + 0x7fffu + ((t >> 16) & 1u)) >> 16;
  return (unsigned short)r;
}

DEVICE void async_cp16(const void* g, void* lds) {
  __builtin_amdgcn_global_load_lds((const __attribute__((address_space(1))) void*)g,
                                   (__attribute__((address_space(3))) void*)lds, 16, 0, 0);
}

// epilogue LDS tile swizzle: row t (256B rows), byte col d2; bijective per row,
// spreads both row-major 16B reads and col-major scalar reads across banks.
DEVICE int lsw(int t, int d2) {
  return t * 256 + (d2 ^ ((((t & 7) ^ ((t >> 3) & 7)) << 4)));
}

// ===== merged prep: x convert + RoPE table + both weight transposes =========
// blocks [0,4096): x fp32->bf16 (8/thread)
// blocks [4096,4608): cs table
// blocks [4608,7680): w_qkv transpose (2048 x 6144 -> 6144 x 2048 bf16)
// blocks [7680,8704): w_out transpose (2048 x 2048)
__global__ __launch_bounds__(256)
void prep_all_kernel(const float* __restrict__ x, unsigned short* __restrict__ xb,
                     float2* __restrict__ cs,
                     const float* __restrict__ wq, unsigned short* __restrict__ wqT,
                     const float* __restrict__ wo, unsigned short* __restrict__ woT) {
  __shared__ float tile[64 * 65];
  int bid = blockIdx.x, tid = threadIdx.x;
  if (bid < 4096) {
    int i = (bid * 256 + tid) * 8;
    float4 v0 = *(const float4*)(x + i);
    float4 v1 = *(const float4*)(x + i + 4);
    bf16x8 o;
    o[0] = (short)f2bf(v0.x); o[1] = (short)f2bf(v0.y);
    o[2] = (short)f2bf(v0.z); o[3] = (short)f2bf(v0.w);
    o[4] = (short)f2bf(v1.x); o[5] = (short)f2bf(v1.y);
    o[6] = (short)f2bf(v1.z); o[7] = (short)f2bf(v1.w);
    *(bf16x8*)(xb + i) = o;
  } else if (bid < 4608) {
    int t = (bid - 4096) * 4 + (tid >> 6);   // 0..2047
    int j = tid & 63;
    float inv = exp2f(-(float)j * 0.20764137662f);   // 10000^(-j/64)
    float ang = (float)t * inv;
    cs[t * 64 + j] = make_float2(cosf(ang), sinf(ang));
  } else {
    const float* in; unsigned short* out; int R, C, c0, r0;
    if (bid < 7680) {
      int idx = bid - 4608;                  // 96 x 32 tiles
      in = wq; out = wqT; R = Dc; C = NQKV;
      c0 = (idx % 96) * 64; r0 = (idx / 96) * 64;
    } else {
      int idx = bid - 7680;                  // 32 x 32 tiles
      in = wo; out = woT; R = Dc; C = Dc;
      c0 = (idx & 31) * 64; r0 = (idx >> 5) * 64;
    }
#pragma unroll
    for (int it = 0; it < 4; ++it) {
      int idx = it * 256 + tid;
      int r = idx >> 4, c = (idx & 15) * 4;
      float4 v = *(const float4*)&in[(size_t)(r0 + r) * C + c0 + c];
      tile[r * 65 + c] = v.x; tile[r * 65 + c + 1] = v.y;
      tile[r * 65 + c + 2] = v.z; tile[r * 65 + c + 3] = v.w;
    }
    __syncthreads();
#pragma unroll
    for (int it = 0; it < 2; ++it) {
      int idx = it * 256 + tid;
      int r = idx >> 3, c = (idx & 7) * 8;
      bf16x8 ov;
#pragma unroll
      for (int i = 0; i < 8; ++i) ov[i] = (short)f2bf(tile[(c + i) * 65 + r]);
      *(bf16x8*)&out[(size_t)(c0 + r) * R + r0 + c] = ov;
    }
  }
}

// ========== QKV GEMM with fused RoPE + head-split + V-transpose ============
// (proven single-buffer m97 structure + GROUP_M supertiling)
// Q sector is pre-scaled by scale*log2e so attn's softmax skips the mul.
__global__ __launch_bounds__(256, 2)
void gemm_qkv_kernel(const unsigned short* __restrict__ A,
                     const unsigned short* __restrict__ Bt,
                     const float2* __restrict__ cs,
                     unsigned short* __restrict__ qh,
                     unsigned short* __restrict__ kh,
                     unsigned short* __restrict__ vt) {
  const int N = NQKV, K = Dc;
  __shared__ __align__(16) unsigned short sh[128 * 128];   // 32KB
  unsigned short* As = sh;               // [128*64] main-loop A tile
  unsigned short* Bs = sh + 128 * 64;    // [128*64] main-loop B tile

  int nbx = N >> 7;                      // 48
  int nwg = gridDim.x;                   // 1536
  int wg = blockIdx.x;
  int cpx = nwg >> 3;
  wg = (wg & 7) * cpx + (wg >> 3);       // XCD-contiguous (bijective: nwg%8==0)
  int gsize = nbx * 8;                   // GROUP_M=8 supertiles for L2 reuse
  int g = wg / gsize, rem = wg - g * gsize;
  int by = g * 8 + (rem & 7), bx = rem >> 3;
  int m0 = by << 7, n0 = bx << 7;

  int tid = threadIdx.x, lane = tid & 63, wid = tid >> 6;
  int wm = (wid >> 1) << 6, wn = (wid & 1) << 6;

  f32x4 acc[4][4] = {};

  for (int k0 = 0; k0 < K; k0 += 64) {
    __syncthreads();
#pragma unroll
    for (int r = 0; r < 4; ++r) {
      int p = r * 4096 + wid * 1024 + lane * 16;   // byte offset in tile
      int row = p >> 7;
      int cb = (p & 127) ^ ((row & 7) << 4);       // pre-swizzled source col
      const char* ga = (const char*)A + ((size_t)(m0 + row) * K + k0) * 2 + cb;
      async_cp16(ga, (char*)As + r * 4096 + wid * 1024);
      const char* gb = (const char*)Bt + ((size_t)(n0 + row) * K + k0) * 2 + cb;
      async_cp16(gb, (char*)Bs + r * 4096 + wid * 1024);
    }
    __syncthreads();

#pragma unroll
    for (int ks = 0; ks < 2; ++ks) {
      bf16x8 af[4], bfr[4];
#pragma unroll
      for (int mi = 0; mi < 4; ++mi) {
        int row = wm + mi * 16 + (lane & 15);
        int cb = (ks * 64 + ((lane >> 4) << 4)) ^ ((row & 7) << 4);
        af[mi] = *(const bf16x8*)((const char*)As + row * 128 + cb);
      }
#pragma unroll
      for (int ni = 0; ni < 4; ++ni) {
        int row = wn + ni * 16 + (lane & 15);
        int cb = (ks * 64 + ((lane >> 4) << 4)) ^ ((row & 7) << 4);
        bfr[ni] = *(const bf16x8*)((const char*)Bs + row * 128 + cb);
      }
#pragma unroll
      for (int mi = 0; mi < 4; ++mi)
#pragma unroll
        for (int ni = 0; ni < 4; ++ni)
          acc[mi][ni] = __builtin_amdgcn_mfma_f32_16x16x32_bf16(
              af[mi], bfr[ni], acc[mi][ni], 0, 0, 0);
    }
  }

  // ---- epilogue: acc -> LDS (bf16, swizzled) ----
  __syncthreads();   // all waves done reading As/Bs
#pragma unroll
  for (int mi = 0; mi < 4; ++mi)
#pragma unroll
    for (int ni = 0; ni < 4; ++ni)
#pragma unroll
      for (int r = 0; r < 4; ++r) {
        int t_ = wm + mi * 16 + ((lane >> 4) << 2) + r;
        int d_ = wn + ni * 16 + (lane & 15);
        *(unsigned short*)((char*)sh + lsw(t_, d_ * 2)) = f2bf(acc[mi][ni][r]);
      }
  __syncthreads();

  int sector = n0 >> 11;                 // 0=Q, 1=K, 2=V
  int h = (n0 & 2047) >> 7;
  if (sector < 2) {
    unsigned short* dst = sector ? kh : qh;
    // Q pre-scaled by scale*log2e = 1/sqrt(128) * log2(e)
    float qsc = sector ? 1.0f : 0.12752627383538357f;
#pragma unroll
    for (int it = 0; it < 4; ++it) {
      int idx = it * 256 + tid;
      int r = idx >> 3, j0 = (idx & 7) * 8;
      int m = m0 + r;
      int t = m & (Tc - 1), b = m >> 11;
      bf16x8 o1, o2;
#pragma unroll
      for (int i = 0; i < 8; ++i) {
        float q1 = bf2f(*(const unsigned short*)((const char*)sh + lsw(r, (j0 + i) * 2)));
        float q2 = bf2f(*(const unsigned short*)((const char*)sh + lsw(r, (j0 + i + 64) * 2)));
        float2 c = cs[t * 64 + j0 + i];
        o1[i] = (short)f2bf((q1 * c.x - q2 * c.y) * qsc);
        o2[i] = (short)f2bf((q2 * c.x + q1 * c.y) * qsc);
      }
      size_t ob = ((size_t)(b * Hc + h) * Tc + t) * HD;
      *(bf16x8*)(dst + ob + j0) = o1;
      *(bf16x8*)(dst + ob + 64 + j0) = o2;
    }
  } else {
    int bh = (m0 >> 11) * Hc + h;
    int tb = m0 & (Tc - 1);
#pragma unroll
    for (int it = 0; it < 8; ++it) {
      int idx = it * 256 + tid;
      int d = idx >> 4, tc = idx & 15;
      bf16x8 o;
#pragma unroll
      for (int i = 0; i < 8; ++i)
        o[i] = (short)*(const unsigned short*)((const char*)sh + lsw(tc * 8 + i, d * 2));
      *(bf16x8*)(vt + (size_t)(bh * HD + d) * Tc + tb + tc * 8) = o;
    }
  }
}

// ---------------- 128x128 bf16 GEMM (m97 structure), for out-proj -----------
__global__ __launch_bounds__(256, 2)
void gemm_bt_kernel(const unsigned short* __restrict__ A,
                    const unsigned short* __restrict__ Bt,
                    float* __restrict__ C, int M, int N, int K) {
  __shared__ unsigned short As[128 * 64];
  __shared__ unsigned short Bs[128 * 64];

  int nbx = N >> 7;
  int nwg = gridDim.x;
  int wg = blockIdx.x;
  int cpx = nwg >> 3;
  wg = (wg & 7) * cpx + (wg >> 3);
  int gsize = nbx * 8;
  int g = wg / gsize, rem = wg - g * gsize;
  int by = g * 8 + (rem & 7), bx = rem >> 3;
  int m0 = by << 7, n0 = bx << 7;

  int tid = threadIdx.x, lane = tid & 63, wid = tid >> 6;
  int wm = (wid >> 1) << 6, wn = (wid & 1) << 6;

  f32x4 acc[4][4] = {};

  for (int k0 = 0; k0 < K; k0 += 64) {
    __syncthreads();
#pragma unroll
    for (int r = 0; r < 4; ++r) {
      int p = r * 4096 + wid * 1024 + lane * 16;
      int row = p >> 7;
      int cb = (p & 127) ^ ((row & 7) << 4);
      const char* ga = (const char*)A + ((size_t)(m0 + row) * K + k0) * 2 + cb;
      async_cp16(ga, (char*)As + r * 4096 + wid * 1024);
      const char* gb = (const char*)Bt + ((size_t)(n0 + row) * K + k0) * 2 + cb;
      async_cp16(gb, (char*)Bs + r * 4096 + wid * 1024);
    }
    __syncthreads();

#pragma unroll
    for (int ks = 0; ks < 2; ++ks) {
      bf16x8 af[4], bfr[4];
#pragma unroll
      for (int mi = 0; mi < 4; ++mi) {
        int row = wm + mi * 16 + (lane & 15);
        int cb = (ks * 64 + ((lane >> 4) << 4)) ^ ((row & 7) << 4);
        af[mi] = *(const bf16x8*)((const char*)As + row * 128 + cb);
      }
#pragma unroll
      for (int ni = 0; ni < 4; ++ni) {
        int row = wn + ni * 16 + (lane & 15);
        int cb = (ks * 64 + ((lane >> 4) << 4)) ^ ((row & 7) << 4);
        bfr[ni] = *(const bf16x8*)((const char*)Bs + row * 128 + cb);
      }
#pragma unroll
      for (int mi = 0; mi < 4; ++mi)
#pragma unroll
        for (int ni = 0; ni < 4; ++ni)
          acc[mi][ni] = __builtin_amdgcn_mfma_f32_16x16x32_bf16(
              af[mi], bfr[ni], acc[mi][ni], 0, 0, 0);
    }
  }

#pragma unroll
  for (int mi = 0; mi < 4; ++mi)
#pragma unroll
    for (int ni = 0; ni < 4; ++ni)
#pragma unroll
      for (int r = 0; r < 4; ++r) {
        int row = m0 + wm + mi * 16 + ((lane >> 4) << 2) + r;
        int col = n0 + wn + ni * 16 + (lane & 15);
        C[(size_t)row * N + col] = acc[mi][ni][r];
      }
}

// ---------------- causal flash attention (round-8 proven version) -----------
// Q arrives pre-scaled by scale*log2e, so sacc is already in exp2 domain.
__global__ __launch_bounds__(512, 1)
void attn_kernel(const unsigned short* __restrict__ qh,
                 const unsigned short* __restrict__ kh,
                 const unsigned short* __restrict__ vt,
                 unsigned short* __restrict__ ao) {
  int bh = blockIdx.x;                       // 0..31
  int pairp = blockIdx.y;                    // 0..7
  int b = bh >> 4, h = bh & 15;

  __shared__ unsigned short Ks[3][64 * 128];   // 3 x 16KB, 256B rows, swizzled
  __shared__ unsigned short Vs[3][128 * 64];   // 3 x 16KB, V^T rows=d, 128B
  __shared__ unsigned short Ps[8][16 * 64];    // 16KB, per-wave P, 128B rows

  int tid = threadIdx.x, lane = tid & 63, wid = tid >> 6;

  const unsigned short* Kg = kh + (size_t)bh * Tc * HD;
  const unsigned short* Vg = vt + (size_t)bh * HD * Tc;

  auto stage = [&](int kt, int buf) {        // 4 vmem loads per thread
#pragma unroll
    for (int r = 0; r < 2; ++r) {
      int p = r * 8192 + wid * 1024 + lane * 16;
      {
        int row = p >> 8, cb = p & 255;
        const char* g = (const char*)Kg + ((size_t)(kt * 64 + row)) * 256 +
                        (cb ^ ((row & 7) << 4));
        async_cp16(g, (char*)&Ks[buf][0] + r * 8192 + wid * 1024);
      }
      {
        int d = p >> 7, cb = p & 127;
        const char* g = (const char*)Vg + (size_t)d * (Tc * 2) + kt * 128 +
                        (cb ^ ((d & 7) << 4));
        async_cp16(g, (char*)&Vs[buf][0] + r * 8192 + wid * 1024);
      }
    }
  };

#pragma unroll 1
  for (int pass = 0; pass < 2; ++pass) {
    int qt = pass ? (15 - pairp) : pairp;
    const unsigned short* Qg = qh + ((size_t)bh * Tc + qt * 128) * HD;

    // Q fragments direct from global; drain so loop vmcnt counts stay exact
    bf16x8 qf[4];
#pragma unroll
    for (int ks = 0; ks < 4; ++ks) {
      int row = wid * 16 + (lane & 15);
      qf[ks] = *(const bf16x8*)((const char*)Qg + row * 256 + ks * 64 +
                                ((lane >> 4) << 4));
    }
    asm volatile("s_waitcnt vmcnt(0)" ::: "memory");

    f32x4 oacc[8] = {};
    float mrow[4], lrow[4];
#pragma unroll
    for (int r = 0; r < 4; ++r) { mrow[r] = -1e30f; lrow[r] = 0.f; }

    int nkt = 2 * (qt + 1);
    __syncthreads();     // pass boundary: prior pass's LDS reads done
    stage(0, 0);
    stage(1, 1);         // nkt >= 2 always
#pragma unroll 1
    for (int kt = 0; kt < nkt; ++kt) {
      // wait for tile kt (own loads), then barrier -> all threads' loads done
      if (kt + 1 < nkt)
        asm volatile("s_waitcnt vmcnt(4)" ::: "memory");
      else
        asm volatile("s_waitcnt vmcnt(0)" ::: "memory");
      asm volatile("s_barrier" ::: "memory");
      if (kt + 2 < nkt) stage(kt + 2, (kt + 2) % 3);
      int cur = kt % 3;

      // S = Q K^T  (16 x 64), already scaled (Q pre-scaled)
      f32x4 sacc[4] = {};
      __builtin_amdgcn_s_setprio(1);
#pragma unroll
      for (int ks = 0; ks < 4; ++ks) {
#pragma unroll
        for (int ni = 0; ni < 4; ++ni) {
          int row = ni * 16 + (lane & 15);
          int cb = (ks * 64 + ((lane >> 4) << 4)) ^ ((row & 7) << 4);
          bf16x8 kf = *(const bf16x8*)((const char*)&Ks[cur][0] + row * 256 + cb);
          sacc[ni] = __builtin_amdgcn_mfma_f32_16x16x32_bf16(qf[ks], kf,
                                                             sacc[ni], 0, 0, 0);
        }
      }
      __builtin_amdgcn_s_setprio(0);

      // softmax in exp2 domain; defer max & sum (steady path: no cross-lane)
      bool diag = (kt >= 2 * qt);
      float sv[4][4];              // [ni][r]
      float pmax[4];
      bool allok = true;
#pragma unroll
      for (int r = 0; r < 4; ++r) {
        int qrow = qt * 128 + wid * 16 + ((lane >> 4) << 2) + r;
        float mx = -1e30f;
#pragma unroll
        for (int ni = 0; ni < 4; ++ni) {
          float s = sacc[ni][r];
          if (diag) {
            int kcol = kt * 64 + ni * 16 + (lane & 15);
            if (kcol > qrow) s = -1e30f;
          }
          sv[ni][r] = s;
          mx = fmaxf(mx, s);
        }
        pmax[r] = mx;
        allok = allok && (mx <= mrow[r] + 8.f);
      }
      if (!__all(allok)) {         // rare: running max moved -> reduce+rescale
#pragma unroll
        for (int r = 0; r < 4; ++r) {
          float gm = pmax[r];
          gm = fmaxf(gm, __shfl_xor(gm, 1));
          gm = fmaxf(gm, __shfl_xor(gm, 2));
          gm = fmaxf(gm, __shfl_xor(gm, 4));
          gm = fmaxf(gm, __shfl_xor(gm, 8));
          float mnew = fmaxf(mrow[r], gm);
          float fsc = exp2f(mrow[r] - mnew);
          mrow[r] = mnew;
          lrow[r] *= fsc;
#pragma unroll
          for (int nj = 0; nj < 8; ++nj) oacc[nj][r] *= fsc;
        }
      }

      // P = exp2(sv - m); per-lane partial sums; write P (bf16) to LDS
#pragma unroll
      for (int ni = 0; ni < 4; ++ni)
#pragma unroll
        for (int r = 0; r < 4; ++r) {
          float pp = exp2f(sv[ni][r] - mrow[r]);
          lrow[r] += pp;
          int row = ((lane >> 4) << 2) + r;
          int colb = (ni * 16 + (lane & 15)) * 2;
          *(unsigned short*)((char*)&Ps[wid][0] + row * 128 +
                             (colb ^ ((row & 7) << 4))) = f2bf(pp);
        }

      // O += P @ V  (same-wave LDS RAW; compiler inserts lgkmcnt waits)
      __builtin_amdgcn_s_setprio(1);
#pragma unroll
      for (int ks = 0; ks < 2; ++ks) {
        int prow = lane & 15;
        int pcb = (ks * 64 + ((lane >> 4) << 4)) ^ ((prow & 7) << 4);
        bf16x8 pf = *(const bf16x8*)((const char*)&Ps[wid][0] + prow * 128 + pcb);
#pragma unroll
        for (int nj = 0; nj < 8; ++nj) {
          int vrow = nj * 16 + (lane & 15);
          int vcb = (ks * 64 + ((lane >> 4) << 4)) ^ ((vrow & 7) << 4);
          bf16x8 vf = *(const bf16x8*)((const char*)&Vs[cur][0] + vrow * 128 + vcb);
          oacc[nj] = __builtin_amdgcn_mfma_f32_16x16x32_bf16(pf, vf,
                                                             oacc[nj], 0, 0, 0);
        }
      }
      __builtin_amdgcn_s_setprio(0);
    }

    // epilogue: reduce deferred row sums across 16-lane groups, normalize
    float inv[4];
#pragma unroll
    for (int r = 0; r < 4; ++r) {
      float s = lrow[r];
      s += __shfl_xor(s, 1);
      s += __shfl_xor(s, 2);
      s += __shfl_xor(s, 4);
      s += __shfl_xor(s, 8);
      inv[r] = 1.f / s;
    }
#pragma unroll
    for (int nj = 0; nj < 8; ++nj)
#pragma unroll
      for (int r = 0; r < 4; ++r) {
        int trow = qt * 128 + wid * 16 + ((lane >> 4) << 2) + r;
        int col = nj * 16 + (lane & 15);
        ao[((size_t)(b * Tc + trow)) * Dc + h * HD + col] =
            f2bf(oacc[nj][r] * inv[r]);
      }
  }
}

// ---------------- launcher --------------------------------------------------
extern "C" void kernel_launch(void* const* d_in, const int* in_sizes, int n_in,
                              void* d_out, int out_size, void* d_ws,
                              size_t ws_size, hipStream_t stream) {
  const float* x = (const float*)d_in[0];
  const float* w_qkv = (const float*)d_in[1];
  const float* w_out = (const float*)d_in[2];
  float* out = (float*)d_out;

  char* ws = (char*)d_ws;
  size_t off = 0;
  auto alloc = [&](size_t bytes) {
    char* p = ws + off;
    off += (bytes + 255) & ~(size_t)255;
    return p;
  };
  unsigned short* xb    = (unsigned short*)alloc((size_t)MR * Dc * 2);
  unsigned short* wqkvT = (unsigned short*)alloc((size_t)NQKV * Dc * 2);
  unsigned short* woutT = (unsigned short*)alloc((size_t)Dc * Dc * 2);
  unsigned short* qhp   = (unsigned short*)alloc((size_t)MR * Dc * 2);
  unsigned short* khp   = (unsigned short*)alloc((size_t)MR * Dc * 2);
  unsigned short* vtp   = (unsigned short*)alloc((size_t)MR * Dc * 2);
  unsigned short* aop   = (unsigned short*)alloc((size_t)MR * Dc * 2);
  float2* cs            = (float2*)alloc((size_t)Tc * 64 * sizeof(float2));

  prep_all_kernel<<<8704, 256, 0, stream>>>(x, xb, cs, w_qkv, wqkvT, w_out, woutT);
  gemm_qkv_kernel<<<(MR / 128) * (NQKV / 128), 256, 0, stream>>>(
      xb, wqkvT, cs, qhp, khp, vtp);
  attn_kernel<<<dim3(32, 8), 512, 0, stream>>>(qhp, khp, vtp, aop);
  gemm_bt_kernel<<<(MR / 128) * (Dc / 128), 256, 0, stream>>>(
      aop, woutT, out, MR, Dc, Dc);
}